// Round 6
// baseline (684.244 us; speedup 1.0000x reference)
//
#include <hip/hip_runtime.h>
#include <hip/hip_cooperative_groups.h>

namespace cg = cooperative_groups;

#define N_Q   16384
#define C_DIM 128
#define S_CAM 6
#define M_VAL 1400   // 28*50
#define D_Z   8
#define HF    28
#define WF    50
#define QPB   16                 // queries per block (phase 2)
#define NG    (N_Q/QPB)          // 1024 query groups
#define VROWG 525                // 8400/16 row groups (phase 1)

__device__ __forceinline__ float bflo(unsigned u){ return __uint_as_float(u << 16); }
__device__ __forceinline__ float bfhi(unsigned u){ return __uint_as_float(u & 0xffff0000u); }

union SharedU {
  float tile[16][C_DIM];                   // phase 1 staging (8 KB)
  struct {                                 // phase 2 (~33.7 KB)
    float  qs[QPB][C_DIM+4];               // +4 pad: distinct banks per qi; reused as slots
    float  offs[QPB][64];
    float  attns[QPB][32];
    float  logits[QPB][32];
    float4 swt [8][QPB*4+1];               // [p][qi*4+h], +1 row pad
    int4   sidx[8][QPB*4+1];
    int    activ[QPB][S_CAM];
    float  cinv[QPB];
  } p2;
};

__device__ __forceinline__ bool mask_any(const unsigned char* __restrict__ mask,
                                         int mflag, size_t mbase){
  if(mflag==0){
    int any=0;
    #pragma unroll
    for(int d=0;d<D_Z;d++) any |= mask[mbase+d];
    return any!=0;
  } else if(mflag==1){
    const int* mp = (const int*)mask;  int any=0;
    #pragma unroll
    for(int d=0;d<D_Z;d++) any |= mp[mbase+d];
    return any!=0;
  } else {
    const long long* mp = (const long long*)mask;  long long any=0;
    #pragma unroll
    for(int d=0;d<D_Z;d++) any |= mp[mbase+d];
    return any!=0;
  }
}

// ---------------------------------------------------------------------------
// Single cooperative kernel:
//   phase 1: vproj = value @ Wv + bv -> bf16 workspace (+ mask-format sniff)
//   grid.sync()
//   phase 2: q-proj -> softmax -> bilinear gather (bf16, uint4 = 8ch/thread)
//            -> masked avg -> out-proj + residual
// launch_bounds(256,4): 128-VGPR budget — NO SPILLS (round 5: (256,8) spilled
// 343 MB of scratch; WRITE_SIZE 351 MB, VALUBusy 7%).
// ---------------------------------------------------------------------------
__global__ __launch_bounds__(256, 4)
void bev_coop_kernel(const float* __restrict__ value,
                     const float* __restrict__ Wv,
                     const float* __restrict__ bv,
                     unsigned short* __restrict__ vb16,
                     const unsigned char* __restrict__ mask,
                     int* __restrict__ flag,
                     const float* __restrict__ query,
                     const float* __restrict__ query_pos,
                     const float* __restrict__ Wo, const float* __restrict__ bo,
                     const float* __restrict__ Wa, const float* __restrict__ ba,
                     const float* __restrict__ ref,
                     const float* __restrict__ Wout,
                     const float* __restrict__ bout,
                     float* __restrict__ out){
  __shared__ SharedU sh;
  __shared__ int s_cntA, s_cntB;
  const int tid = threadIdx.x;

  // ================= phase 1: value projection =================
  {
    const int col = tid & 127;
    const int rh  = tid >> 7;                  // rows rh*8 .. rh*8+7
    for(int g = blockIdx.x; g < VROWG; g += gridDim.x){
      const int r0 = g*16;
      {
        const float4* src = (const float4*)(value + (size_t)r0*C_DIM);
        float4* dst = (float4*)&sh.tile[0][0];
        dst[tid]       = src[tid];
        dst[tid + 256] = src[tid + 256];
      }
      __syncthreads();
      float acc[8];
      const float bias = bv[col];
      #pragma unroll
      for(int r=0;r<8;r++) acc[r]=bias;
      for(int k=0;k<C_DIM;k+=4){
        const float w0 = Wv[(k+0)*C_DIM + col];
        const float w1 = Wv[(k+1)*C_DIM + col];
        const float w2 = Wv[(k+2)*C_DIM + col];
        const float w3 = Wv[(k+3)*C_DIM + col];
        #pragma unroll
        for(int r=0;r<8;r++){
          const float4 t = *(const float4*)&sh.tile[rh*8+r][k];
          acc[r] += t.x*w0 + t.y*w1 + t.z*w2 + t.w*w3;
        }
      }
      #pragma unroll
      for(int r=0;r<8;r++){
        unsigned u = __float_as_uint(acc[r]);
        u += 0x7fff + ((u >> 16) & 1);         // RNE bf16
        vb16[(size_t)(r0+rh*8+r)*C_DIM + col] = (unsigned short)(u >> 16);
      }
      __syncthreads();
    }
    if(blockIdx.x==0){                         // mask-format sniff
      if(tid==0){ s_cntA=0; s_cntB=0; }
      __syncthreads();
      int a=0, b=0;
      for(int i=tid;i<1024;i+=256){
        const unsigned char v = mask[i];
        if(((i&3)!=0) && v) a=1;
        if(((i&7)==4) && v) b=1;
      }
      if(a) atomicOr(&s_cntA,1);
      if(b) atomicOr(&s_cntB,1);
      __syncthreads();
      if(tid==0) flag[0] = s_cntA ? 0 : (s_cntB ? 1 : 2);
    }
  }

  __threadfence();
  cg::this_grid().sync();

  // ================= phase 2: fused deformable attention =================
  const int mflag = *(volatile const int*)flag;
  const int qi  = tid >> 4;                    // query within block (0..15)
  const int l   = tid & 15;                    // lane within query
  const int gh  = l >> 2;                      // gather: head
  const int gch = gh*32 + (l&3)*8;             // gather: first of 8 channels

  for(int g = blockIdx.x; g < NG; g += gridDim.x){
    const int n0 = g*QPB;
    // ---- q = query + query_pos (padded rows) ----
    {
      const float4* qa = (const float4*)(query     + (size_t)n0*C_DIM);
      const float4* qb = (const float4*)(query_pos + (size_t)n0*C_DIM);
      #pragma unroll
      for(int i=0;i<2;i++){
        const int idx = tid + 256*i;
        const int r = idx >> 5, c4 = idx & 31;
        float4 A = qa[idx], B = qb[idx];
        *(float4*)&sh.p2.qs[r][c4*4] = make_float4(A.x+B.x, A.y+B.y, A.z+B.z, A.w+B.w);
      }
    }
    __syncthreads();
    // ---- offset/attn projections: lane l covers off cols l*4+j, logit cols l*2+j ----
    {
      float ao0 = bo[l*4+0], ao1 = bo[l*4+1], ao2 = bo[l*4+2], ao3 = bo[l*4+3];
      float aa0 = ba[l*2+0], aa1 = ba[l*2+1];
      for(int k=0;k<C_DIM;k++){
        const float qv = sh.p2.qs[qi][k];
        const float4 wo = *(const float4*)&Wo[k*64 + l*4];
        const float2 wa = *(const float2*)&Wa[k*32 + l*2];
        ao0 += qv*wo.x; ao1 += qv*wo.y; ao2 += qv*wo.z; ao3 += qv*wo.w;
        aa0 += qv*wa.x; aa1 += qv*wa.y;
      }
      sh.p2.offs[qi][l*4+0] = ao0;  sh.p2.offs[qi][l*4+1] = ao1;
      sh.p2.offs[qi][l*4+2] = ao2;  sh.p2.offs[qi][l*4+3] = ao3;
      sh.p2.logits[qi][l*2+0] = aa0;  sh.p2.logits[qi][l*2+1] = aa1;
    }
    if(tid < QPB*S_CAM){
      const int q2 = tid / S_CAM, s = tid % S_CAM;
      sh.p2.activ[q2][s] = mask_any(mask, mflag, ((size_t)s*N_Q + (n0+q2))*D_Z) ? 1 : 0;
    }
    __syncthreads();
    if(tid < 64){                              // softmax over P=8: (q2, h)
      const int q2 = tid >> 2, h = tid & 3;
      const float* L = &sh.p2.logits[q2][h*8];
      float mx = L[0];
      #pragma unroll
      for(int p=1;p<8;p++) mx = fmaxf(mx, L[p]);
      float e[8], ssum = 0.f;
      #pragma unroll
      for(int p=0;p<8;p++){ e[p] = __expf(L[p]-mx); ssum += e[p]; }
      const float inv = 1.f/ssum;
      #pragma unroll
      for(int p=0;p<8;p++) sh.p2.attns[q2][h*8+p] = e[p]*inv;
    } else if(tid >= 256-QPB){
      const int q2 = tid - (256-QPB);
      int c = 0;
      #pragma unroll
      for(int s=0;s<S_CAM;s++) c += sh.p2.activ[q2][s];
      sh.p2.cinv[q2] = 1.f / fmaxf((float)c, 1.f);
    }
    __syncthreads();

    // ---- per-camera precompute + gather ----
    float a0=0.f,a1=0.f,a2=0.f,a3=0.f,a4=0.f,a5=0.f,a6=0.f,a7=0.f;
    for(int s=0;s<S_CAM;s++){
      #pragma unroll
      for(int e=tid; e<512; e+=256){           // one lane per (p, q2, h)
        const int p  = e >> 6, rem = e & 63;
        const int q2 = rem >> 2, h = rem & 3;
        const float2 r2 = ((const float2*)(ref + ((size_t)s*N_Q + (n0+q2))*D_Z*2))[p];
        const float x = (r2.x + sh.p2.offs[q2][h*16+p*2+0]*(1.0f/(float)WF))*(float)WF - 0.5f;
        const float y = (r2.y + sh.p2.offs[q2][h*16+p*2+1]*(1.0f/(float)HF))*(float)HF - 0.5f;
        const float x0f = floorf(x), y0f = floorf(y);
        const float fx = x - x0f,    fy = y - y0f;
        const int x0 = (int)x0f, y0 = (int)y0f;
        const int x1 = x0+1,     y1 = y0+1;
        const float at = sh.p2.activ[q2][s] ? sh.p2.attns[q2][h*8+p] : 0.f;
        const float wx0 = (x0>=0 && x0<WF) ? (1.f-fx) : 0.f;
        const float wx1 = (x1>=0 && x1<WF) ? fx       : 0.f;
        const float wy0 = ((y0>=0 && y0<HF) ? (1.f-fy) : 0.f) * at;
        const float wy1 = ((y1>=0 && y1<HF) ? fy       : 0.f) * at;
        const int x0c = min(max(x0,0), WF-1), x1c = min(max(x1,0), WF-1);
        const int y0c = min(max(y0,0), HF-1), y1c = min(max(y1,0), HF-1);
        sh.p2.swt [p][rem] = make_float4(wx0*wy0, wx1*wy0, wx0*wy1, wx1*wy1);
        sh.p2.sidx[p][rem] = make_int4((y0c*WF+x0c)*C_DIM, (y0c*WF+x1c)*C_DIM,
                                       (y1c*WF+x0c)*C_DIM, (y1c*WF+x1c)*C_DIM);
      }
      __syncthreads();
      {   // gather: 8 channels/thread via 16B loads
        const unsigned short* vb = vb16 + (size_t)s*M_VAL*C_DIM + gch;
        #pragma unroll
        for(int p=0;p<8;p++){
          const int4   id = sh.p2.sidx[p][qi*4+gh];
          const float4 w  = sh.p2.swt [p][qi*4+gh];
          const uint4 v00 = *(const uint4*)(vb + id.x);
          const uint4 v01 = *(const uint4*)(vb + id.y);
          const uint4 v10 = *(const uint4*)(vb + id.z);
          const uint4 v11 = *(const uint4*)(vb + id.w);
          a0 += w.x*bflo(v00.x) + w.y*bflo(v01.x) + w.z*bflo(v10.x) + w.w*bflo(v11.x);
          a1 += w.x*bfhi(v00.x) + w.y*bfhi(v01.x) + w.z*bfhi(v10.x) + w.w*bfhi(v11.x);
          a2 += w.x*bflo(v00.y) + w.y*bflo(v01.y) + w.z*bflo(v10.y) + w.w*bflo(v11.y);
          a3 += w.x*bfhi(v00.y) + w.y*bfhi(v01.y) + w.z*bfhi(v10.y) + w.w*bfhi(v11.y);
          a4 += w.x*bflo(v00.z) + w.y*bflo(v01.z) + w.z*bflo(v10.z) + w.w*bflo(v11.z);
          a5 += w.x*bfhi(v00.z) + w.y*bfhi(v01.z) + w.z*bfhi(v10.z) + w.w*bfhi(v11.z);
          a6 += w.x*bflo(v00.w) + w.y*bflo(v01.w) + w.z*bflo(v10.w) + w.w*bflo(v11.w);
          a7 += w.x*bfhi(v00.w) + w.y*bfhi(v01.w) + w.z*bfhi(v10.w) + w.w*bfhi(v11.w);
        }
      }
      __syncthreads();
    }

    // ---- slots (reuse qs) -> out-proj + residual ----
    {
      const float inv = sh.p2.cinv[qi];
      *(float4*)&sh.p2.qs[qi][gch]   = make_float4(a0*inv, a1*inv, a2*inv, a3*inv);
      *(float4*)&sh.p2.qs[qi][gch+4] = make_float4(a4*inv, a5*inv, a6*inv, a7*inv);
    }
    __syncthreads();
    {
      const int c0 = l*8;                      // 8 output cols per lane
      const int n  = n0 + qi;
      const float4 bA = *(const float4*)&bout[c0];
      const float4 bB = *(const float4*)&bout[c0+4];
      const float4 rA = *(const float4*)&query[(size_t)n*C_DIM + c0];
      const float4 rB = *(const float4*)&query[(size_t)n*C_DIM + c0 + 4];
      float o0=bA.x+rA.x, o1=bA.y+rA.y, o2=bA.z+rA.z, o3=bA.w+rA.w;
      float o4=bB.x+rB.x, o5=bB.y+rB.y, o6=bB.z+rB.z, o7=bB.w+rB.w;
      for(int k=0;k<C_DIM;k++){
        const float sv = sh.p2.qs[qi][k];
        const float4 wA = *(const float4*)&Wout[(size_t)k*C_DIM + c0];
        const float4 wB = *(const float4*)&Wout[(size_t)k*C_DIM + c0 + 4];
        o0 += sv*wA.x; o1 += sv*wA.y; o2 += sv*wA.z; o3 += sv*wA.w;
        o4 += sv*wB.x; o5 += sv*wB.y; o6 += sv*wB.z; o7 += sv*wB.w;
      }
      *(float4*)&out[(size_t)n*C_DIM + c0]     = make_float4(o0,o1,o2,o3);
      *(float4*)&out[(size_t)n*C_DIM + c0 + 4] = make_float4(o4,o5,o6,o7);
    }
    __syncthreads();                           // protect LDS before next group
  }
}

extern "C" void kernel_launch(void* const* d_in, const int* in_sizes, int n_in,
                              void* d_out, int out_size, void* d_ws, size_t ws_size,
                              hipStream_t stream){
  const float* query     = (const float*)d_in[0];
  const float* query_pos = (const float*)d_in[1];
  const float* value     = (const float*)d_in[2];
  const float* ref       = (const float*)d_in[3];
  const unsigned char* mask = (const unsigned char*)d_in[4];
  const float* Wv   = (const float*)d_in[5];
  const float* bv   = (const float*)d_in[6];
  const float* Wo   = (const float*)d_in[7];
  const float* bo   = (const float*)d_in[8];
  const float* Wa   = (const float*)d_in[9];
  const float* ba   = (const float*)d_in[10];
  const float* Wout = (const float*)d_in[11];
  const float* bout = (const float*)d_in[12];
  float* out = (float*)d_out;

  int* flag = (int*)d_ws;
  unsigned short* vb16 = (unsigned short*)((char*)d_ws + 64);

  int nb = 0;
  int grid = 768;                              // safe fallback: 3 blocks/CU
  if(hipOccupancyMaxActiveBlocksPerMultiprocessor(&nb, (const void*)bev_coop_kernel,
                                                  256, 0) == hipSuccess && nb > 0){
    long cap = (long)nb * 256;
    grid = (int)(cap < NG ? cap : NG);
  }

  void* kargs[] = {
    (void*)&value, (void*)&Wv, (void*)&bv, (void*)&vb16, (void*)&mask, (void*)&flag,
    (void*)&query, (void*)&query_pos, (void*)&Wo, (void*)&bo, (void*)&Wa, (void*)&ba,
    (void*)&ref, (void*)&Wout, (void*)&bout, (void*)&out
  };
  hipLaunchCooperativeKernel((void*)bev_coop_kernel, dim3(grid), dim3(256),
                             kargs, 0, stream);
}

// Round 7
// 234.570 us; speedup vs baseline: 2.9170x; 2.9170x over previous
//
#include <hip/hip_runtime.h>

#define N_Q   16384
#define C_DIM 128
#define S_CAM 6
#define M_VAL 1400   // 28*50
#define D_Z   8
#define HF    28
#define WF    50
#define QPB   8      // queries per block in the fused kernel

__device__ __forceinline__ float bflo(unsigned u){ return __uint_as_float(u << 16); }
__device__ __forceinline__ float bfhi(unsigned u){ return __uint_as_float(u & 0xffff0000u); }

__device__ __forceinline__ bool mask_any(const unsigned char* __restrict__ mask,
                                         int mflag, size_t mbase){
  if(mflag==0){
    int any=0;
    #pragma unroll
    for(int d=0;d<D_Z;d++) any |= mask[mbase+d];
    return any!=0;
  } else if(mflag==1){
    const int* mp = (const int*)mask;  int any=0;
    #pragma unroll
    for(int d=0;d<D_Z;d++) any |= mp[mbase+d];
    return any!=0;
  } else {
    const long long* mp = (const long long*)mask;  long long any=0;
    #pragma unroll
    for(int d=0;d<D_Z;d++) any |= mp[mbase+d];
    return any!=0;
  }
}

// ---------------------------------------------------------------------------
// v = value @ Wv + bv (8400x128 @ 128x128) -> bf16 workspace.
// 256 threads: col = tid&127, row-half = tid>>7 (8 rows each of 16/block).
// Block 0 piggybacks the bev_mask upload-format sniff (0=u8,1=i32,2=i64).
// ---------------------------------------------------------------------------
__global__ __launch_bounds__(256)
void value_proj_kernel(const float* __restrict__ value,
                       const float* __restrict__ Wv,
                       const float* __restrict__ bv,
                       unsigned short* __restrict__ vb16,
                       const unsigned char* __restrict__ mask,
                       int* __restrict__ flag){
  __shared__ float tile[16][C_DIM];
  __shared__ int s_cntA, s_cntB;
  const int tid = threadIdx.x;
  const int col = tid & 127;
  const int rh  = tid >> 7;
  const int r0  = blockIdx.x * 16;
  if(blockIdx.x==0 && tid==0){ s_cntA=0; s_cntB=0; }
  {
    const float4* src = (const float4*)(value + (size_t)r0*C_DIM);
    float4* dst = (float4*)&tile[0][0];
    dst[tid]       = src[tid];
    dst[tid + 256] = src[tid + 256];
  }
  __syncthreads();
  float acc[8];
  const float bias = bv[col];
  #pragma unroll
  for(int r=0;r<8;r++) acc[r]=bias;
  for(int k=0;k<C_DIM;k+=4){
    const float w0 = Wv[(k+0)*C_DIM + col];
    const float w1 = Wv[(k+1)*C_DIM + col];
    const float w2 = Wv[(k+2)*C_DIM + col];
    const float w3 = Wv[(k+3)*C_DIM + col];
    #pragma unroll
    for(int r=0;r<8;r++){
      const float4 t = *(const float4*)&tile[rh*8+r][k];
      acc[r] += t.x*w0 + t.y*w1 + t.z*w2 + t.w*w3;
    }
  }
  #pragma unroll
  for(int r=0;r<8;r++){
    unsigned u = __float_as_uint(acc[r]);
    u += 0x7fff + ((u >> 16) & 1);             // RNE bf16
    vb16[(size_t)(r0+rh*8+r)*C_DIM + col] = (unsigned short)(u >> 16);
  }
  if(blockIdx.x==0){
    int a=0, b=0;
    for(int i=tid;i<1024;i+=256){
      const unsigned char v = mask[i];
      if(((i&3)!=0) && v) a=1;
      if(((i&7)==4) && v) b=1;
    }
    if(a) atomicOr(&s_cntA,1);
    if(b) atomicOr(&s_cntB,1);
    __syncthreads();
    if(tid==0) flag[0] = s_cntA ? 0 : (s_cntB ? 1 : 2);
  }
}

// ---------------------------------------------------------------------------
// Fused: q-proj (offsets + attn softmax) -> per-camera precompute of bilinear
// weights/indices (conflict-free [p][qi*4+h] LDS layout) -> bf16 uint2 gather
// (4 ch/lane) -> masked camera average -> out-proj + residual.
// launch_bounds(256,6): VGPR cap 85 (round 4 used 52 -> no spill), 6 blk/CU.
// ---------------------------------------------------------------------------
__global__ __launch_bounds__(256, 6)
void fused_deform_kernel(const unsigned short* __restrict__ vb16,
                         const float* __restrict__ query,
                         const float* __restrict__ query_pos,
                         const float* __restrict__ Wo, const float* __restrict__ bo,
                         const float* __restrict__ Wa, const float* __restrict__ ba,
                         const float* __restrict__ ref,
                         const unsigned char* __restrict__ mask,
                         const int* __restrict__ flag,
                         const float* __restrict__ Wout,
                         const float* __restrict__ bout,
                         float* __restrict__ out){
  __shared__ float  qs[QPB][C_DIM+4];        // +4: row bank shift; reused as slots
  __shared__ float  offs[QPB][68];           // 68 mod 32 = 4: q-rows on distinct banks
  __shared__ float  attns[QPB][36];
  __shared__ float  logits[QPB][36];
  __shared__ float4 swt [8][QPB*4+1];        // [p][qi*4+h], +1 row pad
  __shared__ int4   sidx[8][QPB*4+1];
  __shared__ int    activ[QPB][S_CAM];
  __shared__ float  cinv[QPB];

  const int tid = threadIdx.x;
  const int n0  = blockIdx.x * QPB;
  const int mflag = flag[0];
  const int qi = tid >> 5;                   // query in block
  const int l  = tid & 31;                   // lane within query group

  // ---- 1) q = query + query_pos ----
  {
    const float4* qa = (const float4*)(query     + (size_t)n0*C_DIM);
    const float4* qb = (const float4*)(query_pos + (size_t)n0*C_DIM);
    const int r = tid >> 5, c4 = tid & 31;
    float4 A = qa[tid], B = qb[tid];
    *(float4*)&qs[r][c4*4] = make_float4(A.x+B.x, A.y+B.y, A.z+B.z, A.w+B.w);
  }
  __syncthreads();

  // ---- 2) offset/attn projections: lane l -> off cols l, l+32; logit col l ----
  {
    float acc0 = bo[l], acc1 = bo[l+32], acc2 = ba[l];
    for(int k=0;k<C_DIM;k++){
      const float qv = qs[qi][k];
      acc0 += qv * Wo[k*64 + l];
      acc1 += qv * Wo[k*64 + l + 32];
      acc2 += qv * Wa[k*32 + l];
    }
    offs[qi][l]    = acc0;
    offs[qi][l+32] = acc1;
    logits[qi][l]  = acc2;
  }
  if(tid < QPB*S_CAM){
    const int q2 = tid / S_CAM, s = tid % S_CAM;
    activ[q2][s] = mask_any(mask, mflag, ((size_t)s*N_Q + (n0+q2))*D_Z) ? 1 : 0;
  }
  __syncthreads();
  if(tid < 32){                              // softmax over P=8: (q2, h)
    const int q2 = tid >> 2, h = tid & 3;
    const float* L = &logits[q2][h*8];
    float mx = L[0];
    #pragma unroll
    for(int p=1;p<8;p++) mx = fmaxf(mx, L[p]);
    float e[8], ssum = 0.f;
    #pragma unroll
    for(int p=0;p<8;p++){ e[p] = __expf(L[p]-mx); ssum += e[p]; }
    const float inv = 1.f/ssum;
    #pragma unroll
    for(int p=0;p<8;p++) attns[q2][h*8+p] = e[p]*inv;
  } else if(tid >= 256-QPB){
    const int q2 = tid - (256-QPB);
    int c = 0;
    #pragma unroll
    for(int s=0;s<S_CAM;s++) c += activ[q2][s];
    cinv[q2] = 1.f / fmaxf((float)c, 1.f);
  }
  __syncthreads();

  // ---- 3) per-camera precompute (lane = (p, q2, h)) + gather (4 ch/lane) ----
  const int gh  = l >> 3;                    // gather head
  const int gch = gh*32 + (l&7)*4;           // first of 4 channels
  const int pp  = tid >> 5;                  // precompute: point  (0..7)
  const int prem= tid & 31;                  // precompute: q2*4+h (0..31)
  const int pq  = prem >> 2;
  const int phh = prem & 3;
  float ax=0.f, ay=0.f, az=0.f, aw=0.f;

  for(int s=0;s<S_CAM;s++){
    {   // exactly 256 lanes: one per (p, q2, h)
      const float2 r2 = ((const float2*)(ref + ((size_t)s*N_Q + (n0+pq))*D_Z*2))[pp];
      const float x = (r2.x + offs[pq][phh*16+pp*2+0]*(1.0f/(float)WF))*(float)WF - 0.5f;
      const float y = (r2.y + offs[pq][phh*16+pp*2+1]*(1.0f/(float)HF))*(float)HF - 0.5f;
      const float x0f = floorf(x), y0f = floorf(y);
      const float fx = x - x0f,    fy = y - y0f;
      const int x0 = (int)x0f, y0 = (int)y0f;
      const int x1 = x0+1,     y1 = y0+1;
      const float at = activ[pq][s] ? attns[pq][phh*8+pp] : 0.f;
      const float wx0 = (x0>=0 && x0<WF) ? (1.f-fx) : 0.f;
      const float wx1 = (x1>=0 && x1<WF) ? fx       : 0.f;
      const float wy0 = ((y0>=0 && y0<HF) ? (1.f-fy) : 0.f) * at;
      const float wy1 = ((y1>=0 && y1<HF) ? fy       : 0.f) * at;
      const int x0c = min(max(x0,0), WF-1), x1c = min(max(x1,0), WF-1);
      const int y0c = min(max(y0,0), HF-1), y1c = min(max(y1,0), HF-1);
      swt [pp][prem] = make_float4(wx0*wy0, wx1*wy0, wx0*wy1, wx1*wy1);
      sidx[pp][prem] = make_int4((y0c*WF+x0c)*C_DIM, (y0c*WF+x1c)*C_DIM,
                                 (y1c*WF+x0c)*C_DIM, (y1c*WF+x1c)*C_DIM);
    }
    __syncthreads();
    {   // gather: 4 channels/lane via 8B loads
      const unsigned short* vb = vb16 + (size_t)s*M_VAL*C_DIM + gch;
      #pragma unroll
      for(int p=0;p<8;p++){
        const int4   id = sidx[p][qi*4+gh];
        const float4 w  = swt [p][qi*4+gh];
        const uint2 a0 = *(const uint2*)(vb + id.x);
        const uint2 a1 = *(const uint2*)(vb + id.y);
        const uint2 a2 = *(const uint2*)(vb + id.z);
        const uint2 a3 = *(const uint2*)(vb + id.w);
        ax += w.x*bflo(a0.x) + w.y*bflo(a1.x) + w.z*bflo(a2.x) + w.w*bflo(a3.x);
        ay += w.x*bfhi(a0.x) + w.y*bfhi(a1.x) + w.z*bfhi(a2.x) + w.w*bfhi(a3.x);
        az += w.x*bflo(a0.y) + w.y*bflo(a1.y) + w.z*bflo(a2.y) + w.w*bflo(a3.y);
        aw += w.x*bfhi(a0.y) + w.y*bfhi(a1.y) + w.z*bfhi(a2.y) + w.w*bfhi(a3.y);
      }
    }
    __syncthreads();
  }

  // ---- 4) slots (reuse qs) -> out-proj + residual ----
  {
    const float inv = cinv[qi];
    *(float4*)&qs[qi][gch] = make_float4(ax*inv, ay*inv, az*inv, aw*inv);
  }
  __syncthreads();
  {
    const int c4 = l;                        // output cols 4*c4 .. 4*c4+3
    const int n  = n0 + qi;
    const float4 b4 = *(const float4*)&bout[c4*4];
    const float4 r4 = *(const float4*)&query[(size_t)n*C_DIM + c4*4];
    float ox = b4.x + r4.x, oy = b4.y + r4.y, oz = b4.z + r4.z, ow = b4.w + r4.w;
    for(int k=0;k<C_DIM;k++){
      const float sv = qs[qi][k];
      const float4 w = *(const float4*)&Wout[(size_t)k*C_DIM + c4*4];
      ox += sv*w.x; oy += sv*w.y; oz += sv*w.z; ow += sv*w.w;
    }
    *(float4*)&out[(size_t)n*C_DIM + c4*4] = make_float4(ox, oy, oz, ow);
  }
}

extern "C" void kernel_launch(void* const* d_in, const int* in_sizes, int n_in,
                              void* d_out, int out_size, void* d_ws, size_t ws_size,
                              hipStream_t stream){
  const float* query     = (const float*)d_in[0];
  const float* query_pos = (const float*)d_in[1];
  const float* value     = (const float*)d_in[2];
  const float* ref       = (const float*)d_in[3];
  const unsigned char* mask = (const unsigned char*)d_in[4];
  const float* Wv   = (const float*)d_in[5];
  const float* bv   = (const float*)d_in[6];
  const float* Wo   = (const float*)d_in[7];
  const float* bo   = (const float*)d_in[8];
  const float* Wa   = (const float*)d_in[9];
  const float* ba   = (const float*)d_in[10];
  const float* Wout = (const float*)d_in[11];
  const float* bout = (const float*)d_in[12];
  float* out = (float*)d_out;

  int* flag = (int*)d_ws;
  unsigned short* vb16 = (unsigned short*)((char*)d_ws + 64);

  value_proj_kernel<<<(S_CAM*M_VAL)/16, 256, 0, stream>>>(value, Wv, bv, vb16, mask, flag);
  fused_deform_kernel<<<N_Q/QPB, 256, 0, stream>>>(vb16, query, query_pos,
                                                   Wo, bo, Wa, ba, ref, mask, flag,
                                                   Wout, bout, out);
}

// Round 8
// 204.698 us; speedup vs baseline: 3.3427x; 1.1459x over previous
//
#include <hip/hip_runtime.h>

#define N_Q   16384
#define C_DIM 128
#define S_CAM 6
#define M_VAL 1400   // 28*50
#define D_Z   8
#define HF    28
#define WF    50
#define QPB   8      // queries per block in the fused kernel

__device__ __forceinline__ float bflo(unsigned u){ return __uint_as_float(u << 16); }
__device__ __forceinline__ float bfhi(unsigned u){ return __uint_as_float(u & 0xffff0000u); }

__device__ __forceinline__ bool mask_any(const unsigned char* __restrict__ mask,
                                         int mflag, size_t mbase){
  if(mflag==0){
    int any=0;
    #pragma unroll
    for(int d=0;d<D_Z;d++) any |= mask[mbase+d];
    return any!=0;
  } else if(mflag==1){
    const int* mp = (const int*)mask;  int any=0;
    #pragma unroll
    for(int d=0;d<D_Z;d++) any |= mp[mbase+d];
    return any!=0;
  } else {
    const long long* mp = (const long long*)mask;  long long any=0;
    #pragma unroll
    for(int d=0;d<D_Z;d++) any |= mp[mbase+d];
    return any!=0;
  }
}

// ---------------------------------------------------------------------------
// v = value @ Wv + bv (8400x128 @ 128x128) -> bf16 workspace.
// 1050 blocks x 256 threads: 8 rows/block, thread=(col, rowhalf->4 rows).
// Block 0 piggybacks the bev_mask upload-format sniff (0=u8,1=i32,2=i64).
// ---------------------------------------------------------------------------
__global__ __launch_bounds__(256)
void value_proj_kernel(const float* __restrict__ value,
                       const float* __restrict__ Wv,
                       const float* __restrict__ bv,
                       unsigned short* __restrict__ vb16,
                       const unsigned char* __restrict__ mask,
                       int* __restrict__ flag){
  __shared__ float tile[8][C_DIM];
  __shared__ int s_cntA, s_cntB;
  const int tid = threadIdx.x;
  const int col = tid & 127;
  const int rh  = tid >> 7;                    // rows rh*4 .. rh*4+3
  const int r0  = blockIdx.x * 8;
  if(blockIdx.x==0 && tid==0){ s_cntA=0; s_cntB=0; }
  {
    const float4* src = (const float4*)(value + (size_t)r0*C_DIM);
    ((float4*)&tile[0][0])[tid] = src[tid];    // 256 x 16B = 8x128 floats
  }
  __syncthreads();
  float acc[4];
  const float bias = bv[col];
  #pragma unroll
  for(int r=0;r<4;r++) acc[r]=bias;
  for(int k=0;k<C_DIM;k+=4){
    const float w0 = Wv[(k+0)*C_DIM + col];
    const float w1 = Wv[(k+1)*C_DIM + col];
    const float w2 = Wv[(k+2)*C_DIM + col];
    const float w3 = Wv[(k+3)*C_DIM + col];
    #pragma unroll
    for(int r=0;r<4;r++){
      const float4 t = *(const float4*)&tile[rh*4+r][k];
      acc[r] += t.x*w0 + t.y*w1 + t.z*w2 + t.w*w3;
    }
  }
  #pragma unroll
  for(int r=0;r<4;r++){
    unsigned u = __float_as_uint(acc[r]);
    u += 0x7fff + ((u >> 16) & 1);             // RNE bf16
    vb16[(size_t)(r0+rh*4+r)*C_DIM + col] = (unsigned short)(u >> 16);
  }
  if(blockIdx.x==0){
    int a=0, b=0;
    for(int i=tid;i<1024;i+=256){
      const unsigned char v = mask[i];
      if(((i&3)!=0) && v) a=1;
      if(((i&7)==4) && v) b=1;
    }
    if(a) atomicOr(&s_cntA,1);
    if(b) atomicOr(&s_cntB,1);
    __syncthreads();
    if(tid==0) flag[0] = s_cntA ? 0 : (s_cntB ? 1 : 2);
  }
}

// ---------------------------------------------------------------------------
// Fused deformable attention. Gather region is BARRIER-FREE: each lane
// recomputes its point's bilinear weights/indices from LDS broadcasts
// (refs/offs/attns), so all 6 cams x 8 points x 4 corners of loads form one
// straight-line pipelineable stream. launch_bounds(256,4): 128-VGPR budget,
// proven spill-free (caps 85/32 spilled 55/343 MB in rounds 7/5).
// ---------------------------------------------------------------------------
__global__ __launch_bounds__(256, 4)
void fused_deform_kernel(const unsigned short* __restrict__ vb16,
                         const float* __restrict__ query,
                         const float* __restrict__ query_pos,
                         const float* __restrict__ Wo, const float* __restrict__ bo,
                         const float* __restrict__ Wa, const float* __restrict__ ba,
                         const float* __restrict__ ref,
                         const unsigned char* __restrict__ mask,
                         const int* __restrict__ flag,
                         const float* __restrict__ Wout,
                         const float* __restrict__ bout,
                         float* __restrict__ out){
  __shared__ float  qs[QPB][C_DIM+4];        // q staging; reused as slots
  __shared__ float  offs[QPB][68];           // 68 mod 32 = 4: rows on distinct banks
  __shared__ float  attns[QPB][36];
  __shared__ float  logits[QPB][36];
  __shared__ float2 refs[QPB][S_CAM*D_Z];    // [q][s*8+p]
  __shared__ int    activ[QPB][S_CAM];
  __shared__ float  cinv[QPB];

  const int tid = threadIdx.x;
  const int n0  = blockIdx.x * QPB;
  const int mflag = flag[0];
  const int qi = tid >> 5;                   // query in block
  const int l  = tid & 31;                   // lane within query group

  // ---- 0) issue ref prefetch (in flight across the proj matvec) ----
  // entry e -> q = e/48, s = (e%48)/8, p = e%8 ; 384 entries total
  const int e1 = tid;
  const int e2 = tid + 256;
  const int q1 = e1/48, r1 = e1%48;
  float2 ra = ((const float2*)ref)[((size_t)(r1>>3)*N_Q + (n0+q1))*D_Z + (r1&7)];
  float2 rb = make_float2(0.f,0.f);
  if(e2 < QPB*S_CAM*D_Z){
    const int q2 = e2/48, r2i = e2%48;
    rb = ((const float2*)ref)[((size_t)(r2i>>3)*N_Q + (n0+q2))*D_Z + (r2i&7)];
  }

  // ---- 1) q = query + query_pos ----
  {
    const float4* qa = (const float4*)(query     + (size_t)n0*C_DIM);
    const float4* qb = (const float4*)(query_pos + (size_t)n0*C_DIM);
    const int r = tid >> 5, c4 = tid & 31;
    float4 A = qa[tid], B = qb[tid];
    *(float4*)&qs[r][c4*4] = make_float4(A.x+B.x, A.y+B.y, A.z+B.z, A.w+B.w);
  }
  __syncthreads();

  // ---- 2) offset/attn projections + stash refs + activ ----
  {
    float acc0 = bo[l], acc1 = bo[l+32], acc2 = ba[l];
    for(int k=0;k<C_DIM;k++){
      const float qv = qs[qi][k];
      acc0 += qv * Wo[k*64 + l];
      acc1 += qv * Wo[k*64 + l + 32];
      acc2 += qv * Wa[k*32 + l];
    }
    offs[qi][l]    = acc0;
    offs[qi][l+32] = acc1;
    logits[qi][l]  = acc2;
  }
  refs[q1][r1] = ra;
  if(e2 < QPB*S_CAM*D_Z) refs[e2/48][e2%48] = rb;
  if(tid < QPB*S_CAM){
    const int q2 = tid / S_CAM, s = tid % S_CAM;
    activ[q2][s] = mask_any(mask, mflag, ((size_t)s*N_Q + (n0+q2))*D_Z) ? 1 : 0;
  }
  __syncthreads();
  if(tid < 32){                              // softmax over P=8: (q2, h)
    const int q2 = tid >> 2, h = tid & 3;
    const float* L = &logits[q2][h*8];
    float mx = L[0];
    #pragma unroll
    for(int p=1;p<8;p++) mx = fmaxf(mx, L[p]);
    float e[8], ssum = 0.f;
    #pragma unroll
    for(int p=0;p<8;p++){ e[p] = __expf(L[p]-mx); ssum += e[p]; }
    const float inv = 1.f/ssum;
    #pragma unroll
    for(int p=0;p<8;p++) attns[q2][h*8+p] = e[p]*inv;
  } else if(tid >= 256-QPB){
    const int q2 = tid - (256-QPB);
    int c = 0;
    #pragma unroll
    for(int s=0;s<S_CAM;s++) c += activ[q2][s];
    cinv[q2] = 1.f / fmaxf((float)c, 1.f);
  }
  __syncthreads();

  // ---- 3) barrier-free gather: lane = (qi, h, 4ch); per-lane coord math ----
  const int gh  = l >> 3;                    // head
  const int gch = gh*32 + (l&7)*4;           // first of 4 channels
  float ax=0.f, ay=0.f, az=0.f, aw=0.f;

  for(int s=0;s<S_CAM;s++){
    if(!activ[qi][s]) continue;
    const unsigned short* vb = vb16 + (size_t)s*M_VAL*C_DIM + gch;
    #pragma unroll
    for(int p=0;p<8;p++){                    // point p <-> z-anchor d=p (P//D==1)
      const float2 r2 = refs[qi][s*8+p];
      const float ox = offs[qi][gh*16+p*2+0];
      const float oy = offs[qi][gh*16+p*2+1];
      const float x = fmaf(r2.x, (float)WF, ox - 0.5f);
      const float y = fmaf(r2.y, (float)HF, oy - 0.5f);
      const float x0f = floorf(x), y0f = floorf(y);
      const float fx = x - x0f,    fy = y - y0f;
      const int x0 = (int)x0f, y0 = (int)y0f;
      const int x1 = x0+1,     y1 = y0+1;
      const float at = attns[qi][gh*8+p];
      const float wx0 = (x0>=0 && x0<WF) ? (1.f-fx) : 0.f;
      const float wx1 = (x1>=0 && x1<WF) ? fx       : 0.f;
      const float wy0 = ((y0>=0 && y0<HF) ? (1.f-fy) : 0.f) * at;
      const float wy1 = ((y1>=0 && y1<HF) ? fy       : 0.f) * at;
      const int x0c = min(max(x0,0), WF-1), x1c = min(max(x1,0), WF-1);
      const int y0c = min(max(y0,0), HF-1), y1c = min(max(y1,0), HF-1);
      const float w00 = wx0*wy0, w01 = wx1*wy0, w10 = wx0*wy1, w11 = wx1*wy1;
      const uint2 a0 = *(const uint2*)(vb + (y0c*WF+x0c)*C_DIM);
      const uint2 a1 = *(const uint2*)(vb + (y0c*WF+x1c)*C_DIM);
      const uint2 a2 = *(const uint2*)(vb + (y1c*WF+x0c)*C_DIM);
      const uint2 a3 = *(const uint2*)(vb + (y1c*WF+x1c)*C_DIM);
      ax += w00*bflo(a0.x) + w01*bflo(a1.x) + w10*bflo(a2.x) + w11*bflo(a3.x);
      ay += w00*bfhi(a0.x) + w01*bfhi(a1.x) + w10*bfhi(a2.x) + w11*bfhi(a3.x);
      az += w00*bflo(a0.y) + w01*bflo(a1.y) + w10*bflo(a2.y) + w11*bflo(a3.y);
      aw += w00*bfhi(a0.y) + w01*bfhi(a1.y) + w10*bfhi(a2.y) + w11*bfhi(a3.y);
    }
  }

  // ---- 4) slots (reuse qs) -> out-proj + residual ----
  __syncthreads();                           // qs still holds q; safe to overwrite after all lanes done proj reads
  {
    const float inv = cinv[qi];
    *(float4*)&qs[qi][gch] = make_float4(ax*inv, ay*inv, az*inv, aw*inv);
  }
  __syncthreads();
  {
    const int c4 = l;                        // output cols 4*c4 .. 4*c4+3
    const int n  = n0 + qi;
    const float4 b4 = *(const float4*)&bout[c4*4];
    const float4 r4 = *(const float4*)&query[(size_t)n*C_DIM + c4*4];
    float ox = b4.x + r4.x, oy = b4.y + r4.y, oz = b4.z + r4.z, ow = b4.w + r4.w;
    for(int k=0;k<C_DIM;k++){
      const float sv = qs[qi][k];
      const float4 w = *(const float4*)&Wout[(size_t)k*C_DIM + c4*4];
      ox += sv*w.x; oy += sv*w.y; oz += sv*w.z; ow += sv*w.w;
    }
    *(float4*)&out[(size_t)n*C_DIM + c4*4] = make_float4(ox, oy, oz, ow);
  }
}

extern "C" void kernel_launch(void* const* d_in, const int* in_sizes, int n_in,
                              void* d_out, int out_size, void* d_ws, size_t ws_size,
                              hipStream_t stream){
  const float* query     = (const float*)d_in[0];
  const float* query_pos = (const float*)d_in[1];
  const float* value     = (const float*)d_in[2];
  const float* ref       = (const float*)d_in[3];
  const unsigned char* mask = (const unsigned char*)d_in[4];
  const float* Wv   = (const float*)d_in[5];
  const float* bv   = (const float*)d_in[6];
  const float* Wo   = (const float*)d_in[7];
  const float* bo   = (const float*)d_in[8];
  const float* Wa   = (const float*)d_in[9];
  const float* ba   = (const float*)d_in[10];
  const float* Wout = (const float*)d_in[11];
  const float* bout = (const float*)d_in[12];
  float* out = (float*)d_out;

  int* flag = (int*)d_ws;
  unsigned short* vb16 = (unsigned short*)((char*)d_ws + 64);

  value_proj_kernel<<<(S_CAM*M_VAL)/8, 256, 0, stream>>>(value, Wv, bv, vb16, mask, flag);
  fused_deform_kernel<<<N_Q/QPB, 256, 0, stream>>>(vb16, query, query_pos,
                                                   Wo, bo, Wa, ba, ref, mask, flag,
                                                   Wout, bout, out);
}